// Round 1
// 310.708 us; speedup vs baseline: 1.0239x; 1.0239x over previous
//
#include <hip/hip_runtime.h>
#include <math.h>

#define SEQ 2048
#define EMB 2048

typedef _Float16 f16;
typedef unsigned short ushort_t;
typedef __attribute__((ext_vector_type(2))) _Float16 f16x2;
typedef __attribute__((ext_vector_type(4))) _Float16 f16x4;
typedef __attribute__((ext_vector_type(8))) _Float16 f16x8;
typedef __attribute__((ext_vector_type(4))) float f32x4;
typedef __attribute__((ext_vector_type(8))) short bf16x8;
typedef __attribute__((ext_vector_type(4))) unsigned short us4;
typedef __attribute__((ext_vector_type(8))) unsigned short us8;

// async global->LDS, 16B per lane; LDS dest is lane-contiguous from lane0's ptr
__device__ __forceinline__ void gload16(const void* g, void* l) {
  __builtin_amdgcn_global_load_lds((const __attribute__((address_space(1))) unsigned int*)g,
                                   (__attribute__((address_space(3))) unsigned int*)l, 16, 0, 0);
}

__device__ __forceinline__ ushort_t f32_to_bf16(float f) {
  unsigned int u = __builtin_bit_cast(unsigned int, f);
  u += 0x7FFFu + ((u >> 16) & 1u);
  return (ushort_t)(u >> 16);
}

__device__ __forceinline__ unsigned pack2_bf16(float a, float b) {
  unsigned ua = __builtin_bit_cast(unsigned, a) + 0x8000u;
  unsigned ub = __builtin_bit_cast(unsigned, b) + 0x8000u;
  return __builtin_amdgcn_perm(ub, ua, 0x07060302u);
}
__device__ __forceinline__ us4 pack4_bf16(float a, float b, float c, float d) {
  unsigned lo = pack2_bf16(a, b);
  unsigned hi = pack2_bf16(c, d);
  unsigned long long v = ((unsigned long long)hi << 32) | (unsigned long long)lo;
  return __builtin_bit_cast(us4, v);
}

// ---------------- fp32 -> fp16 conversion, 5 tensors in one launch ----------------
__global__ __launch_bounds__(256) void cvt5_kernel(const float* __restrict__ i0,
                                                   const float* __restrict__ i1,
                                                   const float* __restrict__ i2,
                                                   const float* __restrict__ i3,
                                                   const float* __restrict__ i4,
                                                   f16* __restrict__ o0, f16* __restrict__ o1,
                                                   f16* __restrict__ o2, f16* __restrict__ o3,
                                                   f16* __restrict__ o4) {
  int b = blockIdx.x;
  int z = b >> 12;
  const float* in = (z == 0) ? i0 : (z == 1) ? i1 : (z == 2) ? i2 : (z == 3) ? i3 : i4;
  f16* out = (z == 0) ? o0 : (z == 1) ? o1 : (z == 2) ? o2 : (z == 3) ? o3 : o4;
  int i = ((b & 4095) * 256 + threadIdx.x) * 4;
  f32x4 v = *(const f32x4*)(in + i);
  *(f16x4*)(out + i) = __builtin_convertvector(v, f16x4);
}

// ---------------- RoPE tables (double precision, matches numpy) ----------------
__global__ __launch_bounds__(256) void rope_table_kernel(float* __restrict__ cosT,
                                                         float* __restrict__ sinT) {
  int id = blockIdx.x * 256 + threadIdx.x;
  int t = id >> 5, i = id & 31;
  double inv = pow(10000.0, -(double)i / 32.0);
  double ang = (double)t * inv;
  cosT[id] = (float)cos(ang);
  sinT[id] = (float)sin(ang);
}

// ---------------- RoPE apply on q (fused scale) and k, one launch ----------------
__global__ __launch_bounds__(256) void rope2_kernel(f16* __restrict__ q, f16* __restrict__ k,
                                                    const float* __restrict__ cosT,
                                                    const float* __restrict__ sinT) {
  f16* x = blockIdx.y ? k : q;
  const float scale = blockIdx.y ? 1.0f : 16.3222307f;  // sqrt(128)*log2(e) folded into q
  int id = blockIdx.x * 256 + threadIdx.x;
  int i = id & 31;
  int nh2 = (id >> 5) & 31;
  int t = id >> 10;
  float c = cosT[(t << 5) + i], s = sinT[(t << 5) + i];
  int base = t * EMB + nh2 * 64 + 2 * i;
  f16x2 p = *(f16x2*)(x + base);
  float xr = (float)p.x, xi = (float)p.y;
  f16x2 o;
  o.x = (f16)((xr * c - xi * s) * scale);
  o.y = (f16)((xr * s + xi * c) * scale);
  *(f16x2*)(x + base) = o;
}

// ---------------- Fused projection GEMM, BK=32, swizzled LDS ----------------
// z=0->q f16, z=1->k f16, z=2->v bf16 fragment-tiled vbT:
// vbT index for V[t][h*128+d]:
//   ((h*64 + (t>>5))*8 + (d>>4))*512 + (((t>>3)&3)*16 + (d&15))*8 + (t&7)
__global__ __launch_bounds__(256, 3) void proj_gemm_kernel(
    const f16* __restrict__ A, const f16* __restrict__ B0, const f16* __restrict__ B1,
    const f16* __restrict__ B2, f16* __restrict__ qout, f16* __restrict__ kout,
    ushort_t* __restrict__ vtout) {
  const int z = blockIdx.z;
  const f16* __restrict__ B = (z == 0) ? B0 : ((z == 1) ? B1 : B2);
  __shared__ f16 As[128 * 32];
  __shared__ f16 Bs[128 * 32];
  const int tid = threadIdx.x;
  const int wave = tid >> 6, lane = tid & 63;
  const int l16 = lane & 15, quad = lane >> 4;
  const int wm = (wave >> 1) << 6, wn = (wave & 1) << 6;
  const int bm = blockIdx.y << 7, bn = blockIdx.x << 7;

  const int swg = ((lane & 3) ^ ((lane >> 3) & 3)) * 8;
  const f16* Ag = A + (size_t)(bm + wave * 32 + (lane >> 2)) * EMB + swg;
  const f16* Bg = B + (size_t)(bn + wave * 32 + (lane >> 2)) * EMB + swg;
  f16* Asl = &As[wave * 1024 + lane * 8];
  f16* Bsl = &Bs[wave * 1024 + lane * 8];

  const int swr = (quad ^ ((l16 >> 1) & 3)) * 8;
  int aoff[4], boff[4];
#pragma unroll
  for (int i = 0; i < 4; i++) {
    aoff[i] = (wm + i * 16 + l16) * 32 + swr;
    boff[i] = (wn + i * 16 + l16) * 32 + swr;
  }

  f32x4 acc[4][4];
#pragma unroll
  for (int i = 0; i < 4; i++)
#pragma unroll
    for (int j = 0; j < 4; j++) acc[i][j] = (f32x4){0.f, 0.f, 0.f, 0.f};

  for (int k0 = 0; k0 < EMB; k0 += 32) {
    __syncthreads();
    gload16(Ag + k0, Asl);
    gload16(Ag + (size_t)16 * EMB + k0, Asl + 512);
    gload16(Bg + k0, Bsl);
    gload16(Bg + (size_t)16 * EMB + k0, Bsl + 512);
    __syncthreads();
    f16x8 af[4], bf[4];
#pragma unroll
    for (int mi = 0; mi < 4; mi++) af[mi] = *(const f16x8*)&As[aoff[mi]];
#pragma unroll
    for (int ni = 0; ni < 4; ni++) bf[ni] = *(const f16x8*)&Bs[boff[ni]];
#pragma unroll
    for (int mi = 0; mi < 4; mi++)
#pragma unroll
      for (int ni = 0; ni < 4; ni++)
        acc[mi][ni] = __builtin_amdgcn_mfma_f32_16x16x32_f16(af[mi], bf[ni], acc[mi][ni], 0, 0, 0);
  }

#pragma unroll
  for (int mi = 0; mi < 4; mi++) {
#pragma unroll
    for (int ni = 0; ni < 4; ni++) {
      int row0 = bm + wm + mi * 16 + quad * 4;  // C/D: col=l16, row=quad*4+reg
      int col = bn + wn + ni * 16 + l16;
      if (z == 2) {
        us4 o;
#pragma unroll
        for (int rg = 0; rg < 4; rg++) o[rg] = f32_to_bf16(acc[mi][ni][rg]);
        int hidx = col >> 7, d = col & 127, t = row0;
        size_t idx = ((size_t)((hidx * 64 + (t >> 5)) * 8 + (d >> 4))) * 512 +
                     (((t >> 3) & 3) * 16 + (d & 15)) * 8 + (t & 7);
        *(us4*)&vtout[idx] = o;
      } else {
        f16* Co = (z == 0) ? qout : kout;
#pragma unroll
        for (int rg = 0; rg < 4; rg++)
          Co[(size_t)(row0 + rg) * EMB + col] = (f16)acc[mi][ni][rg];
      }
    }
  }
}

// ---------------- Output GEMM: C = attn * wout^T, f32 out, 128x64 tiles, BK=32 ----------
__global__ __launch_bounds__(256, 2) void out_gemm_kernel(const f16* __restrict__ A,
                                                          const f16* __restrict__ B,
                                                          float* __restrict__ C) {
  __shared__ f16 As[128 * 32];
  __shared__ f16 Bs[64 * 32];
  const int tid = threadIdx.x;
  const int wave = tid >> 6, lane = tid & 63;
  const int l16 = lane & 15, quad = lane >> 4;
  const int wm = (wave >> 1) << 6, wn = (wave & 1) << 5;
  const int bm = blockIdx.y << 7, bn = blockIdx.x << 6;

  const int swg = ((lane & 3) ^ ((lane >> 3) & 3)) * 8;
  const f16* Ag = A + (size_t)(bm + wave * 32 + (lane >> 2)) * EMB + swg;
  const f16* Bg = B + (size_t)(bn + wave * 16 + (lane >> 2)) * EMB + swg;
  f16* Asl = &As[wave * 1024 + lane * 8];
  f16* Bsl = &Bs[wave * 512 + lane * 8];

  const int swr = (quad ^ ((l16 >> 1) & 3)) * 8;
  int aoff[4], boff[2];
#pragma unroll
  for (int i = 0; i < 4; i++) aoff[i] = (wm + i * 16 + l16) * 32 + swr;
#pragma unroll
  for (int i = 0; i < 2; i++) boff[i] = (wn + i * 16 + l16) * 32 + swr;

  f32x4 acc[4][2];
#pragma unroll
  for (int i = 0; i < 4; i++)
#pragma unroll
    for (int j = 0; j < 2; j++) acc[i][j] = (f32x4){0.f, 0.f, 0.f, 0.f};

  for (int k0 = 0; k0 < EMB; k0 += 32) {
    __syncthreads();
    gload16(Ag + k0, Asl);
    gload16(Ag + (size_t)16 * EMB + k0, Asl + 512);
    gload16(Bg + k0, Bsl);
    __syncthreads();
    f16x8 af[4], bf[2];
#pragma unroll
    for (int mi = 0; mi < 4; mi++) af[mi] = *(const f16x8*)&As[aoff[mi]];
#pragma unroll
    for (int ni = 0; ni < 2; ni++) bf[ni] = *(const f16x8*)&Bs[boff[ni]];
#pragma unroll
    for (int mi = 0; mi < 4; mi++)
#pragma unroll
      for (int ni = 0; ni < 2; ni++)
        acc[mi][ni] = __builtin_amdgcn_mfma_f32_16x16x32_f16(af[mi], bf[ni], acc[mi][ni], 0, 0, 0);
  }

#pragma unroll
  for (int mi = 0; mi < 4; mi++) {
#pragma unroll
    for (int ni = 0; ni < 2; ni++) {
      int row0 = bm + wm + mi * 16 + quad * 4;
      int col = bn + wn + ni * 16 + l16;
#pragma unroll
      for (int rg = 0; rg < 4; rg++)
        C[(size_t)(row0 + rg) * EMB + col] = acc[mi][ni][rg];
    }
  }
}

// ---------------- Differential attention v5 ----------------
// 512-thread blocks, 8 waves = (hh=wave>>2, qs=wave&3), 16 q rows per wave.
// Grid (h 16, qblk 32) = 512 blocks, 2/CU (80 KB) -> 16 waves/CU (2x v4 occupancy).
// Staging roles: waves 0..3 stage K (conflict-free pattern: lane reads dim chunk
// (lane&3)*8 + j*32 of key sw*16+(lane>>2); per-j LDS tile index is lane-uniform,
// writes land contiguous 1KB per tile). Waves 4..7 stage V (linear copy of vbT).
// K,V double-buffered, register prefetch, one barrier per iteration.
// Softmax bias -28.8539 folded into QK accumulator init (MFMA C-in).
// Ks tile T = hh*8 + kt*4 + mt : entry[lane*8+j] = K[mt*16+l16][hh*64+kt*32+quad*8+j]
// Vt tile T = kk*8 + dt       : entry[lane*8+j] = V[key32=quad*8+j of half kk][dim=dt*16+l16]
// Ps[wave][kk][lane*8+j]      = P[key32=quad*8+j][q=l16]
__global__ __launch_bounds__(512, 4) void diff_attn_v5(
    const f16* __restrict__ qb, const f16* __restrict__ kb, const ushort_t* __restrict__ vbT,
    const float* __restrict__ lq1, const float* __restrict__ lq2,
    const float* __restrict__ lk1, const float* __restrict__ lk2,
    const float* __restrict__ subw, f16* __restrict__ attnb) {
  const int h = blockIdx.x;     // head fastest -> 2 heads per XCD stay L2-resident
  const int qblk = blockIdx.y;
  const int tid = threadIdx.x;
  const int wave = tid >> 6, lane = tid & 63;
  const int l16 = lane & 15, quad = lane >> 4;
  const int hh = wave >> 2, qs = wave & 3;

  __shared__ f16 Ks[2][8192];           // 32 KB
  __shared__ ushort_t Vt[2][8192];      // 32 KB
  __shared__ ushort_t Ps[8][2][512];    // 16 KB

  // ---- Q B-frags (q pre-scaled by sqrt(128)*log2e at rope) ----
  const int qrow0 = qblk * 64 + qs * 16;
  f16x8 qf[2];  // [kt]
#pragma unroll
  for (int kt = 0; kt < 2; kt++)
    qf[kt] = *(const f16x8*)(qb + (size_t)(qrow0 + l16) * EMB + h * 128 + hh * 64 + kt * 32 +
                             quad * 8);

  f32x4 O[8];  // [dim-tile]
#pragma unroll
  for (int mt = 0; mt < 8; mt++) O[mt] = (f32x4){0.f, 0.f, 0.f, 0.f};
  float lsum = 0.f;

  // ---- staging addresses (wave-uniform role select) ----
  const bool isK = (wave < 4);
  const int sw = wave & 3;
  const ushort_t* sg =
      isK ? (const ushort_t*)(kb + (size_t)(sw * 16 + (lane >> 2)) * EMB + h * 128 +
                              (lane & 3) * 8)
          : vbT + ((size_t)h << 18) + sw * 2048 + lane * 8;
  const int gchunk = isK ? 32 : 512;                 // ushorts between j-chunks
  const size_t gstep = isK ? (size_t)64 * EMB : 8192; // ushorts per kv-step
  int soff[4];
#pragma unroll
  for (int j = 0; j < 4; j++)
    soff[j] = isK ? (((j >> 1) * 8 + (j & 1) * 4 + sw) * 512 +
                     ((lane & 3) * 16 + (lane >> 2)) * 8)
                  : (sw * 2048 + j * 512 + lane * 8);
  ushort_t* sb[2] = {isK ? (ushort_t*)&Ks[0][0] : &Vt[0][0],
                     isK ? (ushort_t*)&Ks[1][0] : &Vt[1][0]};

  // ---- initial tile 0 into buf 0 ----
  {
    us8 sreg[4];
#pragma unroll
    for (int j = 0; j < 4; j++) sreg[j] = *(const us8*)(sg + j * gchunk);
#pragma unroll
    for (int j = 0; j < 4; j++) *(us8*)&sb[0][soff[j]] = sreg[j];
    __syncthreads();
  }

  auto step = [&](const f16* KsC, const ushort_t* VtC, ushort_t* sbN, int it) {
    // register prefetch of tile it+1 (hidden behind the whole compute phase)
    const int nxt = (it + 1 < 32) ? (it + 1) : 0;
    us8 sreg[4];
#pragma unroll
    for (int j = 0; j < 4; j++)
      sreg[j] = *(const us8*)(sg + (size_t)nxt * gstep + j * gchunk);

    // ---- S^T = K·Q^T (this wave's half), exp2, P -> LDS (bf16) ----
#pragma unroll
    for (int mt = 0; mt < 4; mt++) {
      f16x8 ka0 = *(const f16x8*)&KsC[(hh * 8 + mt) * 512 + lane * 8];
      f16x8 ka1 = *(const f16x8*)&KsC[(hh * 8 + 4 + mt) * 512 + lane * 8];
      f32x4 c = (f32x4){-28.8539008f, -28.8539008f, -28.8539008f, -28.8539008f};
      c = __builtin_amdgcn_mfma_f32_16x16x32_f16(ka0, qf[0], c, 0, 0, 0);
      c = __builtin_amdgcn_mfma_f32_16x16x32_f16(ka1, qf[1], c, 0, 0, 0);
      float p0 = __builtin_exp2f(c[0]);
      float p1 = __builtin_exp2f(c[1]);
      float p2 = __builtin_exp2f(c[2]);
      float p3 = __builtin_exp2f(c[3]);
      lsum += (p0 + p1) + (p2 + p3);
      us4 pb = pack4_bf16(p0, p1, p2, p3);
      int poff = (((mt & 1) * 2 + (quad >> 1)) * 16 + l16) * 8 + (quad & 1) * 4;
      *(us4*)&Ps[wave][mt >> 1][poff] = pb;
    }
    // same-wave Ps write->read: compiler inserts lgkmcnt, no barrier needed

    // ---- O^T += V·P ----
#pragma unroll
    for (int kk = 0; kk < 2; kk++) {
      bf16x8 pf = *(const bf16x8*)&Ps[wave][kk][lane * 8];
#pragma unroll
      for (int mt = 0; mt < 8; mt++) {
        bf16x8 va = *(const bf16x8*)&VtC[(kk * 8 + mt) * 512 + lane * 8];
        O[mt] = __builtin_amdgcn_mfma_f32_16x16x32_bf16(va, pf, O[mt], 0, 0, 0);
      }
    }

    // ---- write next tile into the other buffer (nobody reads it this iter) ----
#pragma unroll
    for (int j = 0; j < 4; j++) *(us8*)&sbN[soff[j]] = sreg[j];
    __syncthreads();
  };

  for (int it = 0; it < 32; it += 2) {
    step(Ks[0], Vt[0], sb[1], it);
    step(Ks[1], Vt[1], sb[0], it + 1);
  }

  // ---- lambda ----
  float d1 = 0.f, d2 = 0.f;
  for (int i = 0; i < 64; i++) {
    d1 += lq1[i] * lk1[i];
    d2 += lq2[i] * lk2[i];
  }
  const float lam = __expf(d1) - __expf(d2) + 0.783605767f;

  // ---- per-q softmax denominator (reduce over quads) ----
  float s = lsum;
  s += __shfl_xor(s, 16);
  s += __shfl_xor(s, 32);
  const float inv = (hh == 0) ? (1.f / s) : (lam / s);

  // ---- cross-half combine through LDS (reuse Ks area, 32 KB) ----
  float* Obuf = (float*)&Ks[0][0];
  if (hh == 1) {
#pragma unroll
    for (int mt = 0; mt < 8; mt++) {
      f32x4 v = O[mt] * inv;
      *(f32x4*)&Obuf[(qs * 8 + mt) * 256 + lane * 4] = v;
    }
  }
  __syncthreads();
  if (hh == 0) {
    f32x4 swv[8];
#pragma unroll
    for (int mt = 0; mt < 8; mt++) swv[mt] = *(const f32x4*)(subw + mt * 16 + quad * 4);
    float a[8][4];
    float ms = 0.f;
#pragma unroll
    for (int mt = 0; mt < 8; mt++) {
      f32x4 o1 = *(const f32x4*)&Obuf[(qs * 8 + mt) * 256 + lane * 4];
#pragma unroll
      for (int rg = 0; rg < 4; rg++) {
        float v = O[mt][rg] * inv - o1[rg];
        a[mt][rg] = v;
        ms += v * v;
      }
    }
    ms += __shfl_xor(ms, 16);
    ms += __shfl_xor(ms, 32);
    const float rms = rsqrtf(ms * (1.f / 128.f) + 1e-5f);
    const int t_g = qrow0 + l16;
#pragma unroll
    for (int mt = 0; mt < 8; mt++) {
      f16x4 o;
#pragma unroll
      for (int rg = 0; rg < 4; rg++) o[rg] = (f16)(a[mt][rg] * rms * swv[mt][rg]);
      *(f16x4*)(attnb + (size_t)t_g * EMB + h * 128 + mt * 16 + quad * 4) = o;
    }
  }
}

// ---------------- launcher ----------------
extern "C" void kernel_launch(void* const* d_in, const int* in_sizes, int n_in,
                              void* d_out, int out_size, void* d_ws, size_t ws_size,
                              hipStream_t stream) {
  const float* x    = (const float*)d_in[0];
  const float* wq   = (const float*)d_in[1];
  const float* wk   = (const float*)d_in[2];
  const float* wv   = (const float*)d_in[3];
  const float* wout = (const float*)d_in[4];
  const float* lq1  = (const float*)d_in[5];
  const float* lq2  = (const float*)d_in[6];
  const float* lk1  = (const float*)d_in[7];
  const float* lk2  = (const float*)d_in[8];
  const float* subw = (const float*)d_in[9];
  float* out = (float*)d_out;

  char* ws = (char*)d_ws;
  const size_t MB = 1024 * 1024;
  f16* xb    = (f16*)(ws + 0 * MB);
  f16* wqb   = (f16*)(ws + 8 * MB);
  f16* wkb   = (f16*)(ws + 16 * MB);
  f16* wvb   = (f16*)(ws + 24 * MB);
  f16* woutb = (f16*)(ws + 32 * MB);
  f16* qb    = (f16*)(ws + 40 * MB);
  f16* kb    = (f16*)(ws + 48 * MB);
  ushort_t* vbT = (ushort_t*)(ws + 56 * MB);  // bf16, fragment-tiled per head
  f16* attnb = (f16*)(ws + 64 * MB);
  float* cosT = (float*)(ws + 72 * MB);
  float* sinT = (float*)(ws + 72 * MB + 262144);

  dim3 b256(256);
  cvt5_kernel<<<5 * 4096, b256, 0, stream>>>(x, wq, wk, wv, wout, xb, wqb, wkb, wvb, woutb);
  rope_table_kernel<<<256, b256, 0, stream>>>(cosT, sinT);

  proj_gemm_kernel<<<dim3(16, 16, 3), b256, 0, stream>>>(xb, wqb, wkb, wvb, qb, kb, vbT);

  rope2_kernel<<<dim3(8192, 2), b256, 0, stream>>>(qb, kb, cosT, sinT);

  diff_attn_v5<<<dim3(16, 32), dim3(512), 0, stream>>>(qb, kb, vbT, lq1, lq2, lk1, lk2, subw,
                                                       attnb);

  out_gemm_kernel<<<dim3(32, 16), b256, 0, stream>>>(attnb, woutb, out);
}

// Round 2
// 309.604 us; speedup vs baseline: 1.0276x; 1.0036x over previous
//
#include <hip/hip_runtime.h>
#include <math.h>

#define SEQ 2048
#define EMB 2048

typedef _Float16 f16;
typedef unsigned short ushort_t;
typedef __attribute__((ext_vector_type(2))) _Float16 f16x2;
typedef __attribute__((ext_vector_type(4))) _Float16 f16x4;
typedef __attribute__((ext_vector_type(8))) _Float16 f16x8;
typedef __attribute__((ext_vector_type(4))) float f32x4;
typedef __attribute__((ext_vector_type(16))) float f32x16;
typedef __attribute__((ext_vector_type(8))) short bf16x8;
typedef __attribute__((ext_vector_type(4))) unsigned short us4;
typedef __attribute__((ext_vector_type(8))) unsigned short us8;
typedef __attribute__((ext_vector_type(4))) unsigned int uint4v;

// async global->LDS, 16B per lane; LDS dest is lane-contiguous from lane0's ptr
__device__ __forceinline__ void gload16(const void* g, void* l) {
  __builtin_amdgcn_global_load_lds((const __attribute__((address_space(1))) unsigned int*)g,
                                   (__attribute__((address_space(3))) unsigned int*)l, 16, 0, 0);
}

__device__ __forceinline__ ushort_t f32_to_bf16(float f) {
  unsigned int u = __builtin_bit_cast(unsigned int, f);
  u += 0x7FFFu + ((u >> 16) & 1u);
  return (ushort_t)(u >> 16);
}

// packed f32x2 -> bf16x2 in one VALU op (RNE)
__device__ __forceinline__ unsigned cvt_pk_bf16_2(float lo, float hi) {
  unsigned r;
  asm("v_cvt_pk_bf16_f32 %0, %1, %2" : "=v"(r) : "v"(lo), "v"(hi));
  return r;
}

// ---------------- fp32 -> fp16 conversion, 5 tensors in one launch ----------------
__global__ __launch_bounds__(256) void cvt5_kernel(const float* __restrict__ i0,
                                                   const float* __restrict__ i1,
                                                   const float* __restrict__ i2,
                                                   const float* __restrict__ i3,
                                                   const float* __restrict__ i4,
                                                   f16* __restrict__ o0, f16* __restrict__ o1,
                                                   f16* __restrict__ o2, f16* __restrict__ o3,
                                                   f16* __restrict__ o4) {
  int b = blockIdx.x;
  int z = b >> 12;
  const float* in = (z == 0) ? i0 : (z == 1) ? i1 : (z == 2) ? i2 : (z == 3) ? i3 : i4;
  f16* out = (z == 0) ? o0 : (z == 1) ? o1 : (z == 2) ? o2 : (z == 3) ? o3 : o4;
  int i = ((b & 4095) * 256 + threadIdx.x) * 4;
  f32x4 v = *(const f32x4*)(in + i);
  *(f16x4*)(out + i) = __builtin_convertvector(v, f16x4);
}

// ---------------- RoPE tables (double precision, matches numpy) ----------------
__global__ __launch_bounds__(256) void rope_table_kernel(float* __restrict__ cosT,
                                                         float* __restrict__ sinT) {
  int id = blockIdx.x * 256 + threadIdx.x;
  int t = id >> 5, i = id & 31;
  double inv = pow(10000.0, -(double)i / 32.0);
  double ang = (double)t * inv;
  cosT[id] = (float)cos(ang);
  sinT[id] = (float)sin(ang);
}

// ---------------- RoPE apply on q (fused scale) and k, one launch ----------------
__global__ __launch_bounds__(256) void rope2_kernel(f16* __restrict__ q, f16* __restrict__ k,
                                                    const float* __restrict__ cosT,
                                                    const float* __restrict__ sinT) {
  f16* x = blockIdx.y ? k : q;
  const float scale = blockIdx.y ? 1.0f : 16.3222307f;  // sqrt(128)*log2(e) folded into q
  int id = blockIdx.x * 256 + threadIdx.x;
  int i = id & 31;
  int nh2 = (id >> 5) & 31;
  int t = id >> 10;
  float c = cosT[(t << 5) + i], s = sinT[(t << 5) + i];
  int base = t * EMB + nh2 * 64 + 2 * i;
  f16x2 p = *(f16x2*)(x + base);
  float xr = (float)p.x, xi = (float)p.y;
  f16x2 o;
  o.x = (f16)((xr * c - xi * s) * scale);
  o.y = (f16)((xr * s + xi * c) * scale);
  *(f16x2*)(x + base) = o;
}

// ---------------- Fused projection GEMM, BK=32, swizzled LDS ----------------
// z=0->q f16, z=1->k f16, z=2->v bf16 fragment-tiled vbT for 32x32x16 PV:
// vbT index for V[t][h*128+d] (kb=t>>6, kc=(t>>4)&3, hi8=(t>>3)&1, j=t&7, dt=d>>5, dr=d&31):
//   (((h*32+kb)*4+kc)*4+dt)*512 + (hi8*32+dr)*8 + j
// i.e. A-frag tile per (kc 16-key chunk, dt 32-dim tile): entry[lane*8+j] =
//   V[key16 = (lane>>5)*8+j][dim32 = lane&31]   (mfma_32x32x16 A order).
__global__ __launch_bounds__(256, 3) void proj_gemm_kernel(
    const f16* __restrict__ A, const f16* __restrict__ B0, const f16* __restrict__ B1,
    const f16* __restrict__ B2, f16* __restrict__ qout, f16* __restrict__ kout,
    ushort_t* __restrict__ vtout) {
  const int z = blockIdx.z;
  const f16* __restrict__ B = (z == 0) ? B0 : ((z == 1) ? B1 : B2);
  __shared__ f16 As[128 * 32];
  __shared__ f16 Bs[128 * 32];
  const int tid = threadIdx.x;
  const int wave = tid >> 6, lane = tid & 63;
  const int l16 = lane & 15, quad = lane >> 4;
  const int wm = (wave >> 1) << 6, wn = (wave & 1) << 6;
  const int bm = blockIdx.y << 7, bn = blockIdx.x << 7;

  const int swg = ((lane & 3) ^ ((lane >> 3) & 3)) * 8;
  const f16* Ag = A + (size_t)(bm + wave * 32 + (lane >> 2)) * EMB + swg;
  const f16* Bg = B + (size_t)(bn + wave * 32 + (lane >> 2)) * EMB + swg;
  f16* Asl = &As[wave * 1024 + lane * 8];
  f16* Bsl = &Bs[wave * 1024 + lane * 8];

  const int swr = (quad ^ ((l16 >> 1) & 3)) * 8;
  int aoff[4], boff[4];
#pragma unroll
  for (int i = 0; i < 4; i++) {
    aoff[i] = (wm + i * 16 + l16) * 32 + swr;
    boff[i] = (wn + i * 16 + l16) * 32 + swr;
  }

  f32x4 acc[4][4];
#pragma unroll
  for (int i = 0; i < 4; i++)
#pragma unroll
    for (int j = 0; j < 4; j++) acc[i][j] = (f32x4){0.f, 0.f, 0.f, 0.f};

  for (int k0 = 0; k0 < EMB; k0 += 32) {
    __syncthreads();
    gload16(Ag + k0, Asl);
    gload16(Ag + (size_t)16 * EMB + k0, Asl + 512);
    gload16(Bg + k0, Bsl);
    gload16(Bg + (size_t)16 * EMB + k0, Bsl + 512);
    __syncthreads();
    f16x8 af[4], bf[4];
#pragma unroll
    for (int mi = 0; mi < 4; mi++) af[mi] = *(const f16x8*)&As[aoff[mi]];
#pragma unroll
    for (int ni = 0; ni < 4; ni++) bf[ni] = *(const f16x8*)&Bs[boff[ni]];
#pragma unroll
    for (int mi = 0; mi < 4; mi++)
#pragma unroll
      for (int ni = 0; ni < 4; ni++)
        acc[mi][ni] = __builtin_amdgcn_mfma_f32_16x16x32_f16(af[mi], bf[ni], acc[mi][ni], 0, 0, 0);
  }

#pragma unroll
  for (int mi = 0; mi < 4; mi++) {
#pragma unroll
    for (int ni = 0; ni < 4; ni++) {
      int row0 = bm + wm + mi * 16 + quad * 4;  // C/D: col=l16, row=quad*4+reg
      int col = bn + wn + ni * 16 + l16;
      if (z == 2) {
        us4 o;
#pragma unroll
        for (int rg = 0; rg < 4; rg++) o[rg] = f32_to_bf16(acc[mi][ni][rg]);
        int hidx = col >> 7, d = col & 127, t = row0;  // t..t+3 share all bits above t&7
        size_t idx = ((((size_t)hidx * 32 + (t >> 6)) * 4 + ((t >> 4) & 3)) * 4 + (d >> 5)) * 512 +
                     (((t >> 3) & 1) * 32 + (d & 31)) * 8 + (t & 7);
        *(us4*)&vtout[idx] = o;
      } else {
        f16* Co = (z == 0) ? qout : kout;
#pragma unroll
        for (int rg = 0; rg < 4; rg++)
          Co[(size_t)(row0 + rg) * EMB + col] = (f16)acc[mi][ni][rg];
      }
    }
  }
}

// ---------------- Output GEMM: C = attn * wout^T, f32 out, 128x64 tiles, BK=32 ----------
__global__ __launch_bounds__(256, 2) void out_gemm_kernel(const f16* __restrict__ A,
                                                          const f16* __restrict__ B,
                                                          float* __restrict__ C) {
  __shared__ f16 As[128 * 32];
  __shared__ f16 Bs[64 * 32];
  const int tid = threadIdx.x;
  const int wave = tid >> 6, lane = tid & 63;
  const int l16 = lane & 15, quad = lane >> 4;
  const int wm = (wave >> 1) << 6, wn = (wave & 1) << 5;
  const int bm = blockIdx.y << 7, bn = blockIdx.x << 6;

  const int swg = ((lane & 3) ^ ((lane >> 3) & 3)) * 8;
  const f16* Ag = A + (size_t)(bm + wave * 32 + (lane >> 2)) * EMB + swg;
  const f16* Bg = B + (size_t)(bn + wave * 16 + (lane >> 2)) * EMB + swg;
  f16* Asl = &As[wave * 1024 + lane * 8];
  f16* Bsl = &Bs[wave * 512 + lane * 8];

  const int swr = (quad ^ ((l16 >> 1) & 3)) * 8;
  int aoff[4], boff[2];
#pragma unroll
  for (int i = 0; i < 4; i++) aoff[i] = (wm + i * 16 + l16) * 32 + swr;
#pragma unroll
  for (int i = 0; i < 2; i++) boff[i] = (wn + i * 16 + l16) * 32 + swr;

  f32x4 acc[4][2];
#pragma unroll
  for (int i = 0; i < 4; i++)
#pragma unroll
    for (int j = 0; j < 2; j++) acc[i][j] = (f32x4){0.f, 0.f, 0.f, 0.f};

  for (int k0 = 0; k0 < EMB; k0 += 32) {
    __syncthreads();
    gload16(Ag + k0, Asl);
    gload16(Ag + (size_t)16 * EMB + k0, Asl + 512);
    gload16(Bg + k0, Bsl);
    __syncthreads();
    f16x8 af[4], bf[2];
#pragma unroll
    for (int mi = 0; mi < 4; mi++) af[mi] = *(const f16x8*)&As[aoff[mi]];
#pragma unroll
    for (int ni = 0; ni < 2; ni++) bf[ni] = *(const f16x8*)&Bs[boff[ni]];
#pragma unroll
    for (int mi = 0; mi < 4; mi++)
#pragma unroll
      for (int ni = 0; ni < 2; ni++)
        acc[mi][ni] = __builtin_amdgcn_mfma_f32_16x16x32_f16(af[mi], bf[ni], acc[mi][ni], 0, 0, 0);
  }

#pragma unroll
  for (int mi = 0; mi < 4; mi++) {
#pragma unroll
    for (int ni = 0; ni < 2; ni++) {
      int row0 = bm + wm + mi * 16 + quad * 4;
      int col = bn + wn + ni * 16 + l16;
#pragma unroll
      for (int rg = 0; rg < 4; rg++)
        C[(size_t)(row0 + rg) * EMB + col] = acc[mi][ni][rg];
    }
  }
}

// ---------------- Differential attention v6: 32x32 MFMA, in-register P ----------------
// 256 threads, 4 waves = (hh=wave>>1, qs=wave&1), 32 q-rows per wave, 64 per block.
// Grid (h 16, qblk 32) = 512 blocks, 2/CU (64 KB LDS each).
// Staging: both K and V via global_load_lds (per-lane swizzled global src, linear LDS
// dest). Wave w stages K tiles w*4+j2 (hh_s=w>>1, kb_s=w&1, c=j2) and V tiles w*4+j2.
// Ks tile T=hh*8+kb*4+c: entry[l*8+j] = K[kb*32+(l&31)][hh*64+c*16+(l>>5)*8+j]
// Vt tile T=kc*4+dt:     entry[l*8+j] = V[kc*16+(l>>5)*8+j][dt*32+(l&31)]
// QK^T via mfma_32x32x16_f16 (S^T: col=lane&31=q, row=(r&3)+8*(r>>2)+4*hi=key);
// P -> bf16 PV B-frags entirely in registers via v_cvt_pk_bf16_f32 + permlane32_swap.
__global__ __launch_bounds__(256, 2) void diff_attn_v6(
    const f16* __restrict__ qb, const f16* __restrict__ kb, const ushort_t* __restrict__ vbT,
    const float* __restrict__ lq1, const float* __restrict__ lq2,
    const float* __restrict__ lk1, const float* __restrict__ lk2,
    const float* __restrict__ subw, f16* __restrict__ attnb) {
  const int h = blockIdx.x;  // head fastest -> heads stay L2-resident per XCD
  const int qblk = blockIdx.y;
  const int tid = threadIdx.x;
  const int wave = tid >> 6, lane = tid & 63;
  const int l32 = lane & 31, hi = lane >> 5;
  const int hh = wave >> 1, qs = wave & 1;

  __shared__ f16 Ks[2][8192];       // 2 x 16 KB (64 keys x 128 dims per buf)
  __shared__ ushort_t Vt[2][8192];  // 2 x 16 KB

  // ---- Q B-frags (q pre-scaled by sqrt(128)*log2e at rope): col=q=l32, k=hi*8+j ----
  const int qrow0 = qblk * 64 + qs * 32;
  f16x8 qf[4];
#pragma unroll
  for (int c = 0; c < 4; c++)
    qf[c] = *(const f16x8*)(qb + (size_t)(qrow0 + l32) * EMB + h * 128 + hh * 64 + c * 16 + hi * 8);

  f32x16 O[4];  // [dim-tile]; col=q=l32, row=(r&3)+8*(r>>2)+4*hi = dim within tile
#pragma unroll
  for (int dt = 0; dt < 4; dt++)
#pragma unroll
    for (int s2 = 0; s2 < 16; s2++) O[dt][s2] = 0.f;
  float lsum = 0.f;

  // ---- staging source addresses (per-lane swizzled global, linear LDS dest) ----
  const int hhs = wave >> 1, kbs = wave & 1;
  const f16* kgp = kb + (size_t)(kbs * 32 + l32) * EMB + h * 128 + hhs * 64 + hi * 8;
  const ushort_t* vgp = vbT + ((size_t)h * 32) * 8192 + (size_t)wave * 2048 + lane * 8;

  // ---- initial tile 0 into buf 0 ----
#pragma unroll
  for (int j2 = 0; j2 < 4; j2++) gload16(kgp + j2 * 16, &Ks[0][(wave * 4 + j2) * 512]);
#pragma unroll
  for (int j2 = 0; j2 < 4; j2++) gload16(vgp + j2 * 512, &Vt[0][(wave * 4 + j2) * 512]);
  __syncthreads();

  auto step = [&](int cbuf, int nit) {
    // async-stage tile nit into the other buffer; in flight through this compute phase
    if (nit < 32) {
#pragma unroll
      for (int j2 = 0; j2 < 4; j2++)
        gload16(kgp + (size_t)nit * (64 * EMB) + j2 * 16, &Ks[cbuf ^ 1][(wave * 4 + j2) * 512]);
#pragma unroll
      for (int j2 = 0; j2 < 4; j2++)
        gload16(vgp + (size_t)nit * 8192 + j2 * 512, &Vt[cbuf ^ 1][(wave * 4 + j2) * 512]);
    }

    const f16* KsC = &Ks[cbuf][0];
    const ushort_t* VtC = &Vt[cbuf][0];
    bf16x8 pf[4];  // PV B-frags for the 4 16-key chunks of this 64-key tile

#pragma unroll
    for (int kbi = 0; kbi < 2; kbi++) {
      f32x16 acc;
#pragma unroll
      for (int s2 = 0; s2 < 16; s2++) acc[s2] = -28.8539008f;  // softmax bias in C-init
#pragma unroll
      for (int c = 0; c < 4; c++) {
        f16x8 kf = *(const f16x8*)&KsC[(hh * 8 + kbi * 4 + c) * 512 + lane * 8];
        acc = __builtin_amdgcn_mfma_f32_32x32x16_f16(kf, qf[c], acc, 0, 0, 0);
      }
      float p[16];
#pragma unroll
      for (int s2 = 0; s2 < 16; s2++) p[s2] = __builtin_exp2f(acc[s2]);
      lsum += (((p[0] + p[1]) + (p[2] + p[3])) + ((p[4] + p[5]) + (p[6] + p[7]))) +
              (((p[8] + p[9]) + (p[10] + p[11])) + ((p[12] + p[13]) + (p[14] + p[15])));
      // regs s: key = 16*c2 + (s&3) + 8*(s>>2) + 4*hi; build B-frag (k=hi*8+j) via
      // cvt_pk pairs + permlane32_swap (dst.hi-lanes <-> src.lo-lanes)
#pragma unroll
      for (int c2 = 0; c2 < 2; c2++) {
        unsigned w0 = cvt_pk_bf16_2(p[8 * c2 + 0], p[8 * c2 + 1]);
        unsigned w1 = cvt_pk_bf16_2(p[8 * c2 + 2], p[8 * c2 + 3]);
        unsigned w2 = cvt_pk_bf16_2(p[8 * c2 + 4], p[8 * c2 + 5]);
        unsigned w3 = cvt_pk_bf16_2(p[8 * c2 + 6], p[8 * c2 + 7]);
        asm("v_permlane32_swap_b32 %0, %1" : "+v"(w0), "+v"(w2));
        asm("v_permlane32_swap_b32 %0, %1" : "+v"(w1), "+v"(w3));
        uint4v pw;
        pw.x = w0; pw.y = w1; pw.z = w2; pw.w = w3;
        pf[kbi * 2 + c2] = __builtin_bit_cast(bf16x8, pw);
      }
    }

    // ---- O^T += V * P (A=V frag from LDS, B=P frag in regs) ----
#pragma unroll
    for (int kc = 0; kc < 4; kc++) {
#pragma unroll
      for (int dt = 0; dt < 4; dt++) {
        bf16x8 vf = *(const bf16x8*)&VtC[(kc * 4 + dt) * 512 + lane * 8];
        O[dt] = __builtin_amdgcn_mfma_f32_32x32x16_bf16(vf, pf[kc], O[dt], 0, 0, 0);
      }
    }
    __syncthreads();
  };

  for (int it = 0; it < 32; it += 2) {
    step(0, it + 1);
    step(1, it + 2);
  }

  // ---- lambda ----
  float d1 = 0.f, d2 = 0.f;
  for (int i = 0; i < 64; i++) {
    d1 += lq1[i] * lk1[i];
    d2 += lq2[i] * lk2[i];
  }
  const float lam = __expf(d1) - __expf(d2) + 0.783605767f;

  // ---- per-q softmax denominator (lane + partner lane cover all keys) ----
  float s = lsum + __shfl_xor(lsum, 32);
  const float inv = (hh == 0) ? (1.f / s) : (lam / s);

  // ---- cross-half combine through LDS (reuse Ks area, 32 KB) ----
  float* Obuf = (float*)&Ks[0][0];
  if (hh == 1) {
#pragma unroll
    for (int dt = 0; dt < 4; dt++)
#pragma unroll
      for (int rq = 0; rq < 4; rq++) {
        f32x4 v;
#pragma unroll
        for (int rg = 0; rg < 4; rg++) v[rg] = O[dt][rq * 4 + rg] * inv;
        *(f32x4*)&Obuf[(((qs * 4 + dt) * 4 + rq) * 64 + lane) * 4] = v;
      }
  }
  __syncthreads();
  if (hh == 0) {
    float a[4][16];
    float ms = 0.f;
#pragma unroll
    for (int dt = 0; dt < 4; dt++)
#pragma unroll
      for (int rq = 0; rq < 4; rq++) {
        f32x4 o1 = *(const f32x4*)&Obuf[(((qs * 4 + dt) * 4 + rq) * 64 + lane) * 4];
#pragma unroll
        for (int rg = 0; rg < 4; rg++) {
          float v = O[dt][rq * 4 + rg] * inv - o1[rg];
          a[dt][rq * 4 + rg] = v;
          ms += v * v;
        }
      }
    ms += __shfl_xor(ms, 32);
    const float rms = rsqrtf(ms * (1.f / 128.f) + 1e-5f);
    const int t_g = qrow0 + l32;
#pragma unroll
    for (int dt = 0; dt < 4; dt++)
#pragma unroll
      for (int rq = 0; rq < 4; rq++) {
        f32x4 sw = *(const f32x4*)(subw + dt * 32 + rq * 8 + hi * 4);
        f16x4 o;
#pragma unroll
        for (int rg = 0; rg < 4; rg++) o[rg] = (f16)(a[dt][rq * 4 + rg] * rms * sw[rg]);
        *(f16x4*)(attnb + (size_t)t_g * EMB + h * 128 + dt * 32 + rq * 8 + hi * 4) = o;
      }
  }
}

// ---------------- launcher ----------------
extern "C" void kernel_launch(void* const* d_in, const int* in_sizes, int n_in,
                              void* d_out, int out_size, void* d_ws, size_t ws_size,
                              hipStream_t stream) {
  const float* x    = (const float*)d_in[0];
  const float* wq   = (const float*)d_in[1];
  const float* wk   = (const float*)d_in[2];
  const float* wv   = (const float*)d_in[3];
  const float* wout = (const float*)d_in[4];
  const float* lq1  = (const float*)d_in[5];
  const float* lq2  = (const float*)d_in[6];
  const float* lk1  = (const float*)d_in[7];
  const float* lk2  = (const float*)d_in[8];
  const float* subw = (const float*)d_in[9];
  float* out = (float*)d_out;

  char* ws = (char*)d_ws;
  const size_t MB = 1024 * 1024;
  f16* xb    = (f16*)(ws + 0 * MB);
  f16* wqb   = (f16*)(ws + 8 * MB);
  f16* wkb   = (f16*)(ws + 16 * MB);
  f16* wvb   = (f16*)(ws + 24 * MB);
  f16* woutb = (f16*)(ws + 32 * MB);
  f16* qb    = (f16*)(ws + 40 * MB);
  f16* kb    = (f16*)(ws + 48 * MB);
  ushort_t* vbT = (ushort_t*)(ws + 56 * MB);  // bf16, 32x32-fragment-tiled per head
  f16* attnb = (f16*)(ws + 64 * MB);
  float* cosT = (float*)(ws + 72 * MB);
  float* sinT = (float*)(ws + 72 * MB + 262144);

  dim3 b256(256);
  cvt5_kernel<<<5 * 4096, b256, 0, stream>>>(x, wq, wk, wv, wout, xb, wqb, wkb, wvb, woutb);
  rope_table_kernel<<<256, b256, 0, stream>>>(cosT, sinT);

  proj_gemm_kernel<<<dim3(16, 16, 3), b256, 0, stream>>>(xb, wqb, wkb, wvb, qb, kb, vbT);

  rope2_kernel<<<dim3(8192, 2), b256, 0, stream>>>(qb, kb, cosT, sinT);

  diff_attn_v6<<<dim3(16, 32), b256, 0, stream>>>(qb, kb, vbT, lq1, lq2, lk1, lk2, subw, attnb);

  out_gemm_kernel<<<dim3(32, 16), b256, 0, stream>>>(attnb, woutb, out);
}